// Round 1
// baseline (133.091 us; speedup 1.0000x reference)
//
#include <hip/hip_runtime.h>

#define DEG 3
#define NSAMP 20
#define BROWS 65536
#define NKNOT 64
#define ROWS_PER_BLOCK 4
#define NBLOCKS (BROWS / ROWS_PER_BLOCK) /* 16384 */

// One wave (64 lanes) per row. Row data = 64 knot-triples (knot,cx,cy) = 192
// floats = 768 B per tensor, staged to LDS via 48 float4 loads.
__global__ __launch_bounds__(256) void bspline_loss_main(
    const float* __restrict__ pred, const float* __restrict__ tru,
    float* __restrict__ partials)
{
    __shared__ float lds[ROWS_PER_BLOCK][2][192];
    __shared__ float wsum[ROWS_PER_BLOCK];

    const int tid  = threadIdx.x;
    const int wave = tid >> 6;
    const int lane = tid & 63;
    const int row  = blockIdx.x * ROWS_PER_BLOCK + wave;

    if (lane < 48) {
        const float4 p4 = ((const float4*)(pred + (size_t)row * 192))[lane];
        const float4 t4 = ((const float4*)(tru  + (size_t)row * 192))[lane];
        ((float4*)lds[wave][0])[lane] = p4;
        ((float4*)lds[wave][1])[lane] = t4;
    }
    __syncthreads();

    float rx = 0.f, ry = 0.f;
    if (lane < 40) {
        const int sel = (lane >= 20) ? 1 : 0;
        const int s   = sel ? lane - 20 : lane;
        const float* d = lds[wave][sel];   // [64] x (knot, cx, cy)

        // low = 0 always (kf[3] is a leading zero); high = knots[60]
        const float high = d[3 * 60];
        const float t = ((float)s * (1.0f / 19.0f)) * high;

        // cnt = upper_bound over knots[0..59]; searchsorted result s_idx = cnt+3,
        // base control-point index = s_idx - DEG = cnt
        int lo = 0, hi = 60;
        while (lo < hi) {
            int mid = (lo + hi) >> 1;
            if (d[3 * mid] <= t) lo = mid + 1; else hi = mid;
        }
        const int cnt = lo;

        float px[4], py[4], pw[4];
        #pragma unroll
        for (int k = 0; k < 4; ++k) {
            px[k] = d[3 * (cnt + k) + 1];
            py[k] = d[3 * (cnt + k) + 2];
            pw[k] = 1.0f;
        }
        // kf[m] = (m < 4) ? 0 : knots[m-4]
        #pragma unroll
        for (int l = 1; l <= DEG; ++l) {
            #pragma unroll
            for (int k = DEG; k >= l; --k) {
                const int i0 = cnt + k;
                const int i1 = cnt + k + (DEG + 1 - l);
                const float ki = (i0 < 4) ? 0.f : d[3 * (i0 - 4)];
                const float kj = (i1 < 4) ? 0.f : d[3 * (i1 - 4)];
                const float denom = kj - ki;
                const float alpha = (denom != 0.f) ? (t - ki) / denom : 0.f;
                const float b0 = 1.0f - alpha;
                px[k] = b0 * px[k - 1] + alpha * px[k];
                py[k] = b0 * py[k - 1] + alpha * py[k];
                pw[k] = b0 * pw[k - 1] + alpha * pw[k];
            }
        }
        rx = px[DEG] / pw[DEG];
        ry = py[DEG] / pw[DEG];
    }

    // pair pred (lanes 0..19) with true (lanes 20..39)
    const float ox = __shfl(rx, lane + 20, 64);
    const float oy = __shfl(ry, lane + 20, 64);
    float acc = 0.f;
    if (lane < 20) {
        const float dx = rx - ox, dy = ry - oy;
        acc = dx * dx + dy * dy;
    }
    #pragma unroll
    for (int off = 32; off >= 1; off >>= 1)
        acc += __shfl_down(acc, off, 64);
    if (lane == 0) wsum[wave] = acc;
    __syncthreads();
    if (tid == 0)
        partials[blockIdx.x] = wsum[0] + wsum[1] + wsum[2] + wsum[3];
}

__global__ __launch_bounds__(256) void bspline_loss_reduce(
    const float* __restrict__ partials, float* __restrict__ out)
{
    const int tid = threadIdx.x;
    double acc = 0.0;
    const float4* p4 = (const float4*)partials;
    #pragma unroll 4
    for (int i = tid; i < NBLOCKS / 4; i += 256) {
        const float4 v = p4[i];
        acc += (double)v.x + (double)v.y + (double)v.z + (double)v.w;
    }
    #pragma unroll
    for (int off = 32; off >= 1; off >>= 1)
        acc += __shfl_down(acc, off, 64);
    __shared__ double ws[4];
    if ((tid & 63) == 0) ws[tid >> 6] = acc;
    __syncthreads();
    if (tid == 0) {
        const double tot = ws[0] + ws[1] + ws[2] + ws[3];
        out[0] = (float)(tot / (double)((long long)BROWS * NSAMP));
    }
}

extern "C" void kernel_launch(void* const* d_in, const int* in_sizes, int n_in,
                              void* d_out, int out_size, void* d_ws, size_t ws_size,
                              hipStream_t stream) {
    const float* pred = (const float*)d_in[0];
    const float* tru  = (const float*)d_in[1];
    // d_in[2] (true_masks) is ignored: reference uses mask = ones.
    float* out      = (float*)d_out;
    float* partials = (float*)d_ws;   // 16384 floats = 64 KB

    bspline_loss_main<<<NBLOCKS, 256, 0, stream>>>(pred, tru, partials);
    bspline_loss_reduce<<<1, 256, 0, stream>>>(partials, out);
}